// Round 14
// baseline (375.056 us; speedup 1.0000x reference)
//
#include <hip/hip_runtime.h>
#include <hip/hip_bf16.h>

// Problem constants
#define L_SEQ   16384
#define D_IO    2048
#define HEADS   16
#define DHEAD   128
#define KDIM    2048
#define KT64    (KDIM / 64)   // 32 K-tiles of BK=64

typedef __attribute__((ext_vector_type(8))) short short8;
typedef __attribute__((ext_vector_type(4))) float floatx4;

typedef const __attribute__((address_space(1))) unsigned int gu_t;
typedef __attribute__((address_space(3))) unsigned int lu_t;

__device__ __forceinline__ unsigned short f2bf(float f) {
  unsigned u = __float_as_uint(f);
  u += 0x7fffu + ((u >> 16) & 1u);   // RNE
  return (unsigned short)(u >> 16);
}
__device__ __forceinline__ float bf2f(unsigned short s) {
  return __uint_as_float(((unsigned)s) << 16);
}

// ---------------- fused prep ----------------
// blocks [0,8192):        E f32->bf16 (grid-stride)
// blocks [8192,12288):    transpose Wv -> Wvt (32x32 tiles)
// blocks [12288,16384):   transpose Wo -> Wot
// blocks [16384,16512):   qk[h][i] = sum_d Wk[i][h*128+d]*q[h][d]  (bf16 out)
__global__ __launch_bounds__(256)
void prep(const float* __restrict__ e_seq,
          const float* __restrict__ q,
          const float* __restrict__ Wk,
          const float* __restrict__ Wv,
          const float* __restrict__ Wo,
          unsigned short* __restrict__ Ebf,
          unsigned short* __restrict__ Wvt,
          unsigned short* __restrict__ Wot,
          unsigned short* __restrict__ QKbf)
{
  __shared__ float tile[32][33];
  const int b = blockIdx.x;
  if (b < 8192) {
    const long n = (long)L_SEQ * D_IO;
    for (long i = ((long)b * 256 + threadIdx.x) * 8; i < n; i += (long)8192 * 256 * 8) {
      const float4 v0 = *(const float4*)(e_seq + i);
      const float4 v1 = *(const float4*)(e_seq + i + 4);
      uint4 r;
      r.x = (unsigned)f2bf(v0.x) | ((unsigned)f2bf(v0.y) << 16);
      r.y = (unsigned)f2bf(v0.z) | ((unsigned)f2bf(v0.w) << 16);
      r.z = (unsigned)f2bf(v1.x) | ((unsigned)f2bf(v1.y) << 16);
      r.w = (unsigned)f2bf(v1.z) | ((unsigned)f2bf(v1.w) << 16);
      *(uint4*)(Ebf + i) = r;
    }
  } else if (b < 16384) {
    const int tb  = b - 8192;
    const int mat = tb >> 12;          // 0=Wv, 1=Wo
    const int idx = tb & 4095;
    const float* S = (mat == 0) ? Wv : Wo;
    unsigned short* D = (mat == 0) ? Wvt : Wot;
    const int bn = (idx & 63) * 32;
    const int bk = (idx >> 6) * 32;
    const int tx = threadIdx.x & 31, ty = threadIdx.x >> 5;
    #pragma unroll
    for (int i = 0; i < 32; i += 8)
      tile[ty + i][tx] = S[(size_t)(bk + ty + i) * D_IO + bn + tx];
    __syncthreads();
    #pragma unroll
    for (int i = 0; i < 32; i += 8)
      D[(size_t)(bn + ty + i) * D_IO + bk + tx] = f2bf(tile[tx][ty + i]);
  } else {
    const int tb = b - 16384;          // 0..127
    const int h = tb >> 3, chunk = tb & 7;
    const int i = chunk * 256 + threadIdx.x;
    const float* wrow = Wk + (size_t)i * D_IO + h * DHEAD;
    const float* qrow = q + h * DHEAD;
    float s = 0.f;
    #pragma unroll
    for (int d = 0; d < DHEAD; d += 4) {
      const float4 wv4 = *(const float4*)(wrow + d);
      const float4 qv4 = *(const float4*)(qrow + d);
      s += wv4.x * qv4.x + wv4.y * qv4.y + wv4.z * qv4.z + wv4.w * qv4.w;
    }
    QKbf[h * D_IO + i] = f2bf(s);
  }
}

// ---------------- scores: S[L][16] = Ebf @ QK^T (MFMA 16x16x32) ----------------
__global__ __launch_bounds__(256)
void scores(const unsigned short* __restrict__ Ebf,
            const unsigned short* __restrict__ QK,
            float* __restrict__ S)
{
  const int lane = threadIdx.x & 63, wave = threadIdx.x >> 6;
  const int row0 = (blockIdx.x * 4 + wave) * 16;
  const int fr = lane & 15, ko = (lane >> 4) * 8;
  const unsigned short* ea = Ebf + (size_t)(row0 + fr) * KDIM + ko;
  const unsigned short* qa = QK + (size_t)fr * KDIM + ko;
  floatx4 acc = (floatx4)0.f;
  #pragma unroll 8
  for (int kt = 0; kt < KDIM / 32; ++kt) {
    const short8 av = *(const short8*)(ea + kt * 32);
    const short8 bv = *(const short8*)(qa + kt * 32);
    acc = __builtin_amdgcn_mfma_f32_16x16x32_bf16(av, bv, acc, 0, 0, 0);
  }
  #pragma unroll
  for (int r = 0; r < 4; ++r)
    S[(size_t)(row0 + (lane >> 4) * 4 + r) * HEADS + fr] = acc[r];
}

// =====================================================================
// 256x256-tile bf16 GEMM — EXACT R6 schedule (frozen; 6/7 perturbations
// regressed). R14 change: bm-FASTEST XCD mapping — each XCD chunk of 64
// consecutive swz shares ONE bn (1 MB B panel, L2-resident); A re-reads
// across XCDs are served by the shared 256 MB L3 (A total = 64 MB).
// =====================================================================
template<int EPI>
__global__ __launch_bounds__(512, 2)
void gemm256(const unsigned short* __restrict__ A,
             const unsigned short* __restrict__ B,
             void* __restrict__ Cout,
             const float* __restrict__ bias,
             const int ldc, const int bmShift)
{
  __shared__ unsigned short lds[65536];

  const int t = threadIdx.x, lane = t & 63, wave = t >> 6;
  const int wm = wave >> 2, wn = wave & 3;

  const int nwg  = (int)(gridDim.x * gridDim.y);
  const int flat = (int)(blockIdx.y * gridDim.x + blockIdx.x);
  const int cpx  = nwg >> 3;
  const int swz  = (flat & 7) * cpx + (flat >> 3);
  const int bm = swz & ((1 << bmShift) - 1);   // bm fastest within XCD chunk
  const int bn = swz >> bmShift;               // one bn per XCD chunk

  const int fr = lane & 15, kq = lane >> 4;
  const int sl0 = ((kq ^ (fr & 7)) & 7) * 8;

  const int srow  = t >> 3;
  const int sslot = (((t & 7) ^ (srow & 7)) & 7) * 8;
  const unsigned short* aSrc = A + (size_t)(bm * 256 + srow) * KDIM + sslot;
  const unsigned short* bSrc = B + (size_t)(bn * 256 + srow) * KDIM + sslot;

  floatx4 acc[8][4];
  #pragma unroll
  for (int m = 0; m < 8; ++m)
    #pragma unroll
    for (int n = 0; n < 4; ++n) acc[m][n] = (floatx4)0.f;

#define STAGE1(srcbase, q, dstoff, ts)                                                        \
    __builtin_amdgcn_global_load_lds((gu_t*)((srcbase) + (size_t)(ts) * 64 +                  \
                                             (size_t)(q) * 64 * KDIM),                        \
                                     (lu_t*)(lds + (dstoff) + wave * 512), 16, 0, 0)

  STAGE1(aSrc, 0, 0, 0);      STAGE1(aSrc, 2, 8192, 0);
  STAGE1(bSrc, 0, 16384, 0);  STAGE1(bSrc, 1, 20480, 0);
  STAGE1(bSrc, 2, 24576, 0);  STAGE1(bSrc, 3, 28672, 0);
  STAGE1(aSrc, 1, 4096, 0);   STAGE1(aSrc, 3, 12288, 0);
  asm volatile("s_waitcnt vmcnt(2)" ::: "memory");
  __builtin_amdgcn_s_barrier();

  short8 aq[4][2], bq0[2][2], bq1[2][2];

  for (int tt = 0; tt < KT64; ++tt) {
    const int s = tt & 1;
    const int ts = (tt + 1 < KT64) ? (tt + 1) : tt;
    const int d = (s ^ 1) * 32768;
    const unsigned short* As = lds + s * 32768;
    const unsigned short* Bs = As + 16384;
    const unsigned short* ArLo = As + (wm * 2) * 4096 + fr * 64;
    const unsigned short* ArHi = ArLo + 4096;
    const unsigned short* Br   = Bs + wn * 4096 + fr * 64;

    // ---- ph0 ----
    #pragma unroll
    for (int m = 0; m < 4; ++m) {
      aq[m][0] = *(const short8*)(ArLo + m * 1024 + sl0);
      aq[m][1] = *(const short8*)(ArLo + m * 1024 + (sl0 ^ 32));
    }
    #pragma unroll
    for (int n = 0; n < 2; ++n) {
      bq0[n][0] = *(const short8*)(Br + n * 1024 + sl0);
      bq0[n][1] = *(const short8*)(Br + n * 1024 + (sl0 ^ 32));
    }
    STAGE1(aSrc, 0, d, ts);
    STAGE1(aSrc, 2, d + 8192, ts);
    __builtin_amdgcn_s_barrier();
    asm volatile("s_waitcnt lgkmcnt(0)" ::: "memory");
    __builtin_amdgcn_sched_barrier(0);
    __builtin_amdgcn_s_setprio(1);
    #pragma unroll
    for (int m = 0; m < 4; ++m)
      #pragma unroll
      for (int n = 0; n < 2; ++n) {
        acc[m][n] = __builtin_amdgcn_mfma_f32_16x16x32_bf16(aq[m][0], bq0[n][0], acc[m][n], 0, 0, 0);
        acc[m][n] = __builtin_amdgcn_mfma_f32_16x16x32_bf16(aq[m][1], bq0[n][1], acc[m][n], 0, 0, 0);
      }
    __builtin_amdgcn_s_setprio(0);
    __builtin_amdgcn_s_barrier();

    // ---- ph1 ----
    #pragma unroll
    for (int n = 0; n < 2; ++n) {
      bq1[n][0] = *(const short8*)(Br + (2 + n) * 1024 + sl0);
      bq1[n][1] = *(const short8*)(Br + (2 + n) * 1024 + (sl0 ^ 32));
    }
    STAGE1(bSrc, 0, d + 16384, ts);
    STAGE1(bSrc, 1, d + 20480, ts);
    __builtin_amdgcn_s_barrier();
    asm volatile("s_waitcnt lgkmcnt(0)" ::: "memory");
    __builtin_amdgcn_sched_barrier(0);
    __builtin_amdgcn_s_setprio(1);
    #pragma unroll
    for (int m = 0; m < 4; ++m)
      #pragma unroll
      for (int n = 0; n < 2; ++n) {
        acc[m][2 + n] = __builtin_amdgcn_mfma_f32_16x16x32_bf16(aq[m][0], bq1[n][0], acc[m][2 + n], 0, 0, 0);
        acc[m][2 + n] = __builtin_amdgcn_mfma_f32_16x16x32_bf16(aq[m][1], bq1[n][1], acc[m][2 + n], 0, 0, 0);
      }
    __builtin_amdgcn_s_setprio(0);
    asm volatile("s_waitcnt vmcnt(4)" ::: "memory");
    __builtin_amdgcn_s_barrier();

    // ---- ph2 ----
    #pragma unroll
    for (int m = 0; m < 4; ++m) {
      aq[m][0] = *(const short8*)(ArHi + m * 1024 + sl0);
      aq[m][1] = *(const short8*)(ArHi + m * 1024 + (sl0 ^ 32));
    }
    STAGE1(bSrc, 2, d + 24576, ts);
    STAGE1(bSrc, 3, d + 28672, ts);
    __builtin_amdgcn_s_barrier();
    asm volatile("s_waitcnt lgkmcnt(0)" ::: "memory");
    __builtin_amdgcn_sched_barrier(0);
    __builtin_amdgcn_s_setprio(1);
    #pragma unroll
    for (int m = 0; m < 4; ++m)
      #pragma unroll
      for (int n = 0; n < 2; ++n) {
        acc[4 + m][2 + n] = __builtin_amdgcn_mfma_f32_16x16x32_bf16(aq[m][0], bq1[n][0], acc[4 + m][2 + n], 0, 0, 0);
        acc[4 + m][2 + n] = __builtin_amdgcn_mfma_f32_16x16x32_bf16(aq[m][1], bq1[n][1], acc[4 + m][2 + n], 0, 0, 0);
      }
    __builtin_amdgcn_s_setprio(0);
    __builtin_amdgcn_s_barrier();

    // ---- ph3 ----
    STAGE1(aSrc, 1, d + 4096, ts);
    STAGE1(aSrc, 3, d + 12288, ts);
    __builtin_amdgcn_s_setprio(1);
    #pragma unroll
    for (int m = 0; m < 4; ++m)
      #pragma unroll
      for (int n = 0; n < 2; ++n) {
        acc[4 + m][n] = __builtin_amdgcn_mfma_f32_16x16x32_bf16(aq[m][0], bq0[n][0], acc[4 + m][n], 0, 0, 0);
        acc[4 + m][n] = __builtin_amdgcn_mfma_f32_16x16x32_bf16(aq[m][1], bq0[n][1], acc[4 + m][n], 0, 0, 0);
      }
    __builtin_amdgcn_s_setprio(0);
    asm volatile("s_waitcnt vmcnt(2)" ::: "memory");
    __builtin_amdgcn_s_barrier();
  }
#undef STAGE1

  asm volatile("s_waitcnt vmcnt(0)" ::: "memory");

  const int crow0 = bm * 256 + wm * 128 + kq * 4;
  const int ccol0 = bn * 256 + wn * 64 + fr;
  if (EPI == 0) {
    unsigned short* C = (unsigned short*)Cout;
    #pragma unroll
    for (int m = 0; m < 8; ++m)
      #pragma unroll
      for (int n = 0; n < 4; ++n)
        #pragma unroll
        for (int r = 0; r < 4; ++r)
          C[(size_t)(crow0 + m * 16 + r) * ldc + ccol0 + n * 16] = f2bf(acc[m][n][r]);
  } else {
    float* C = (float*)Cout;
    #pragma unroll
    for (int n = 0; n < 4; ++n) {
      const float bv_ = bias[ccol0 + n * 16];
      #pragma unroll
      for (int m = 0; m < 8; ++m)
        #pragma unroll
        for (int r = 0; r < 4; ++r)
          C[(size_t)(crow0 + m * 16 + r) * ldc + ccol0 + n * 16] = acc[m][n][r] + bv_;
    }
  }
}

// ---------------- sliding-window pool (scores precomputed) ----------------
__global__ __launch_bounds__(256)
void winpool(const unsigned short* __restrict__ V,
             const float* __restrict__ S,
             unsigned short* __restrict__ P)
{
  const int lane = threadIdx.x & 63, wid = threadIdx.x >> 6;
  const int tg = (int)blockIdx.x * 4 + wid;       // 0..2047
  const int t0 = tg * 8;
  const int h = blockIdx.y;
  const float scale = 0.08838834764831845f;  // 1/sqrt(128)

  float sv[11], v0[11], v1[11];
  #pragma unroll
  for (int i = 0; i < 11; ++i) {
    const int idx = t0 - 3 + i;
    if (idx >= 0) {
      sv[i] = S[(size_t)idx * HEADS + h] * scale;
      const unsigned vv = *(const unsigned*)(V + (size_t)idx * D_IO + h * DHEAD + lane * 2);
      v0[i] = bf2f((unsigned short)(vv & 0xffffu));
      v1[i] = bf2f((unsigned short)(vv >> 16));
    } else {
      sv[i] = -3.0e38f; v0[i] = 0.f; v1[i] = 0.f;
    }
  }

  #pragma unroll
  for (int j = 0; j < 8; ++j) {
    const float mx = fmaxf(fmaxf(sv[j], sv[j + 1]), fmaxf(sv[j + 2], sv[j + 3]));
    float p0 = __expf(sv[j] - mx),     p1 = __expf(sv[j + 1] - mx);
    float p2 = __expf(sv[j + 2] - mx), p3 = __expf(sv[j + 3] - mx);
    const float inv = 1.f / (p0 + p1 + p2 + p3);
    const float o0 = (p0 * v0[j] + p1 * v0[j + 1] + p2 * v0[j + 2] + p3 * v0[j + 3]) * inv;
    const float o1 = (p0 * v1[j] + p1 * v1[j + 1] + p2 * v1[j + 2] + p3 * v1[j + 3]) * inv;
    const unsigned outw = ((unsigned)f2bf(o1) << 16) | (unsigned)f2bf(o0);
    *(unsigned*)(P + (size_t)(t0 + j) * D_IO + h * DHEAD + lane * 2) = outw;
  }
}

// ---------------- launch ----------------
extern "C" void kernel_launch(void* const* d_in, const int* in_sizes, int n_in,
                              void* d_out, int out_size, void* d_ws, size_t ws_size,
                              hipStream_t stream)
{
  const float* e_seq = (const float*)d_in[0];
  const float* q     = (const float*)d_in[1];
  const float* Wk    = (const float*)d_in[2];
  const float* Wv    = (const float*)d_in[3];
  const float* Wo    = (const float*)d_in[4];
  const float* bo    = (const float*)d_in[5];
  float* out = (float*)d_out;

  char* ws = (char*)d_ws;
  unsigned short* Ebf  = (unsigned short*)ws;                         // 64 MB (E bf16; reused as pooled)
  unsigned short* Vbf  = (unsigned short*)(ws + 67108864);            // 64 MB
  unsigned short* Wvt  = (unsigned short*)(ws + 134217728);           // 8 MB
  unsigned short* Wot  = (unsigned short*)(ws + 142606336);           // 8 MB
  unsigned short* QKbf = (unsigned short*)(ws + 150994944);           // 64 KB
  float*          Sbuf = (float*)(ws + 151060480);                    // 1 MB

  // prep: cvt E + transpose Wv,Wo + qk = per-head Wk_slice @ q
  prep<<<16512, 256, 0, stream>>>(e_seq, q, Wk, Wv, Wo, Ebf, Wvt, Wot, QKbf);

  // V = E * Wv   (M=16384, N=2048, K=2048), bf16 out; bmShift=6 (64 bm tiles)
  gemm256<0><<<dim3(8, 64), 512, 0, stream>>>(Ebf, Wvt, Vbf, nullptr, 2048, 6);

  // S = E @ qk^T  ([L,16] f32)
  scores<<<L_SEQ / 64, 256, 0, stream>>>(Ebf, QKbf, Sbuf);

  // pooled (into Ebf, no longer needed)
  winpool<<<dim3(512, HEADS), 256, 0, stream>>>(Vbf, Sbuf, Ebf);

  // out = pooled * Wo + bo   (f32 out + bias); bmShift=6
  gemm256<1><<<dim3(8, 64), 512, 0, stream>>>(Ebf, Wot, out, bo, 2048, 6);
}

// Round 15
// 362.806 us; speedup vs baseline: 1.0338x; 1.0338x over previous
//
#include <hip/hip_runtime.h>
#include <hip/hip_bf16.h>

// Problem constants
#define L_SEQ   16384
#define D_IO    2048
#define HEADS   16
#define DHEAD   128
#define KDIM    2048
#define KT64    (KDIM / 64)   // 32 K-tiles of BK=64

typedef __attribute__((ext_vector_type(8))) short short8;
typedef __attribute__((ext_vector_type(4))) float floatx4;

typedef const __attribute__((address_space(1))) unsigned int gu_t;
typedef __attribute__((address_space(3))) unsigned int lu_t;

__device__ __forceinline__ unsigned short f2bf(float f) {
  unsigned u = __float_as_uint(f);
  u += 0x7fffu + ((u >> 16) & 1u);   // RNE
  return (unsigned short)(u >> 16);
}
__device__ __forceinline__ float bf2f(unsigned short s) {
  return __uint_as_float(((unsigned)s) << 16);
}

// ---------------- fused prep ----------------
// blocks [0,8192):        E f32->bf16 (grid-stride)
// blocks [8192,12288):    transpose Wv -> Wvt (32x32 tiles)
// blocks [12288,16384):   transpose Wo -> Wot
// blocks [16384,16512):   qk[h][i] = sum_d Wk[i][h*128+d]*q[h][d]  (bf16 out)
__global__ __launch_bounds__(256)
void prep(const float* __restrict__ e_seq,
          const float* __restrict__ q,
          const float* __restrict__ Wk,
          const float* __restrict__ Wv,
          const float* __restrict__ Wo,
          unsigned short* __restrict__ Ebf,
          unsigned short* __restrict__ Wvt,
          unsigned short* __restrict__ Wot,
          unsigned short* __restrict__ QKbf)
{
  __shared__ float tile[32][33];
  const int b = blockIdx.x;
  if (b < 8192) {
    const long n = (long)L_SEQ * D_IO;
    for (long i = ((long)b * 256 + threadIdx.x) * 8; i < n; i += (long)8192 * 256 * 8) {
      const float4 v0 = *(const float4*)(e_seq + i);
      const float4 v1 = *(const float4*)(e_seq + i + 4);
      uint4 r;
      r.x = (unsigned)f2bf(v0.x) | ((unsigned)f2bf(v0.y) << 16);
      r.y = (unsigned)f2bf(v0.z) | ((unsigned)f2bf(v0.w) << 16);
      r.z = (unsigned)f2bf(v1.x) | ((unsigned)f2bf(v1.y) << 16);
      r.w = (unsigned)f2bf(v1.z) | ((unsigned)f2bf(v1.w) << 16);
      *(uint4*)(Ebf + i) = r;
    }
  } else if (b < 16384) {
    const int tb  = b - 8192;
    const int mat = tb >> 12;          // 0=Wv, 1=Wo
    const int idx = tb & 4095;
    const float* S = (mat == 0) ? Wv : Wo;
    unsigned short* D = (mat == 0) ? Wvt : Wot;
    const int bn = (idx & 63) * 32;
    const int bk = (idx >> 6) * 32;
    const int tx = threadIdx.x & 31, ty = threadIdx.x >> 5;
    #pragma unroll
    for (int i = 0; i < 32; i += 8)
      tile[ty + i][tx] = S[(size_t)(bk + ty + i) * D_IO + bn + tx];
    __syncthreads();
    #pragma unroll
    for (int i = 0; i < 32; i += 8)
      D[(size_t)(bn + ty + i) * D_IO + bk + tx] = f2bf(tile[tx][ty + i]);
  } else {
    const int tb = b - 16384;          // 0..127
    const int h = tb >> 3, chunk = tb & 7;
    const int i = chunk * 256 + threadIdx.x;
    const float* wrow = Wk + (size_t)i * D_IO + h * DHEAD;
    const float* qrow = q + h * DHEAD;
    float s = 0.f;
    #pragma unroll
    for (int d = 0; d < DHEAD; d += 4) {
      const float4 wv4 = *(const float4*)(wrow + d);
      const float4 qv4 = *(const float4*)(qrow + d);
      s += wv4.x * qv4.x + wv4.y * qv4.y + wv4.z * qv4.z + wv4.w * qv4.w;
    }
    QKbf[h * D_IO + i] = f2bf(s);
  }
}

// ---------------- scores: S[L][16] = Ebf @ QK^T (MFMA 16x16x32) ----------------
__global__ __launch_bounds__(256)
void scores(const unsigned short* __restrict__ Ebf,
            const unsigned short* __restrict__ QK,
            float* __restrict__ S)
{
  const int lane = threadIdx.x & 63, wave = threadIdx.x >> 6;
  const int row0 = (blockIdx.x * 4 + wave) * 16;
  const int fr = lane & 15, ko = (lane >> 4) * 8;
  const unsigned short* ea = Ebf + (size_t)(row0 + fr) * KDIM + ko;
  const unsigned short* qa = QK + (size_t)fr * KDIM + ko;
  floatx4 acc = (floatx4)0.f;
  #pragma unroll 8
  for (int kt = 0; kt < KDIM / 32; ++kt) {
    const short8 av = *(const short8*)(ea + kt * 32);
    const short8 bv = *(const short8*)(qa + kt * 32);
    acc = __builtin_amdgcn_mfma_f32_16x16x32_bf16(av, bv, acc, 0, 0, 0);
  }
  #pragma unroll
  for (int r = 0; r < 4; ++r)
    S[(size_t)(row0 + (lane >> 4) * 4 + r) * HEADS + fr] = acc[r];
}

// =====================================================================
// 256x256-tile bf16 GEMM — EXACT R6 schedule, bn-fastest XCD swizzle
// (measured best, frozen; 7/8 perturbations regressed — do not touch).
// =====================================================================
template<int EPI>
__global__ __launch_bounds__(512, 2)
void gemm256(const unsigned short* __restrict__ A,
             const unsigned short* __restrict__ B,
             void* __restrict__ Cout,
             const float* __restrict__ bias,
             const int ldc, const int bnShift)
{
  __shared__ unsigned short lds[65536];

  const int t = threadIdx.x, lane = t & 63, wave = t >> 6;
  const int wm = wave >> 2, wn = wave & 3;

  const int nwg  = (int)(gridDim.x * gridDim.y);
  const int flat = (int)(blockIdx.y * gridDim.x + blockIdx.x);
  const int cpx  = nwg >> 3;
  const int swz  = (flat & 7) * cpx + (flat >> 3);
  const int bn = swz & ((1 << bnShift) - 1);
  const int bm = swz >> bnShift;

  const int fr = lane & 15, kq = lane >> 4;
  const int sl0 = ((kq ^ (fr & 7)) & 7) * 8;

  const int srow  = t >> 3;
  const int sslot = (((t & 7) ^ (srow & 7)) & 7) * 8;
  const unsigned short* aSrc = A + (size_t)(bm * 256 + srow) * KDIM + sslot;
  const unsigned short* bSrc = B + (size_t)(bn * 256 + srow) * KDIM + sslot;

  floatx4 acc[8][4];
  #pragma unroll
  for (int m = 0; m < 8; ++m)
    #pragma unroll
    for (int n = 0; n < 4; ++n) acc[m][n] = (floatx4)0.f;

#define STAGE1(srcbase, q, dstoff, ts)                                                        \
    __builtin_amdgcn_global_load_lds((gu_t*)((srcbase) + (size_t)(ts) * 64 +                  \
                                             (size_t)(q) * 64 * KDIM),                        \
                                     (lu_t*)(lds + (dstoff) + wave * 512), 16, 0, 0)

  STAGE1(aSrc, 0, 0, 0);      STAGE1(aSrc, 2, 8192, 0);
  STAGE1(bSrc, 0, 16384, 0);  STAGE1(bSrc, 1, 20480, 0);
  STAGE1(bSrc, 2, 24576, 0);  STAGE1(bSrc, 3, 28672, 0);
  STAGE1(aSrc, 1, 4096, 0);   STAGE1(aSrc, 3, 12288, 0);
  asm volatile("s_waitcnt vmcnt(2)" ::: "memory");
  __builtin_amdgcn_s_barrier();

  short8 aq[4][2], bq0[2][2], bq1[2][2];

  for (int tt = 0; tt < KT64; ++tt) {
    const int s = tt & 1;
    const int ts = (tt + 1 < KT64) ? (tt + 1) : tt;
    const int d = (s ^ 1) * 32768;
    const unsigned short* As = lds + s * 32768;
    const unsigned short* Bs = As + 16384;
    const unsigned short* ArLo = As + (wm * 2) * 4096 + fr * 64;
    const unsigned short* ArHi = ArLo + 4096;
    const unsigned short* Br   = Bs + wn * 4096 + fr * 64;

    // ---- ph0 ----
    #pragma unroll
    for (int m = 0; m < 4; ++m) {
      aq[m][0] = *(const short8*)(ArLo + m * 1024 + sl0);
      aq[m][1] = *(const short8*)(ArLo + m * 1024 + (sl0 ^ 32));
    }
    #pragma unroll
    for (int n = 0; n < 2; ++n) {
      bq0[n][0] = *(const short8*)(Br + n * 1024 + sl0);
      bq0[n][1] = *(const short8*)(Br + n * 1024 + (sl0 ^ 32));
    }
    STAGE1(aSrc, 0, d, ts);
    STAGE1(aSrc, 2, d + 8192, ts);
    __builtin_amdgcn_s_barrier();
    asm volatile("s_waitcnt lgkmcnt(0)" ::: "memory");
    __builtin_amdgcn_sched_barrier(0);
    __builtin_amdgcn_s_setprio(1);
    #pragma unroll
    for (int m = 0; m < 4; ++m)
      #pragma unroll
      for (int n = 0; n < 2; ++n) {
        acc[m][n] = __builtin_amdgcn_mfma_f32_16x16x32_bf16(aq[m][0], bq0[n][0], acc[m][n], 0, 0, 0);
        acc[m][n] = __builtin_amdgcn_mfma_f32_16x16x32_bf16(aq[m][1], bq0[n][1], acc[m][n], 0, 0, 0);
      }
    __builtin_amdgcn_s_setprio(0);
    __builtin_amdgcn_s_barrier();

    // ---- ph1 ----
    #pragma unroll
    for (int n = 0; n < 2; ++n) {
      bq1[n][0] = *(const short8*)(Br + (2 + n) * 1024 + sl0);
      bq1[n][1] = *(const short8*)(Br + (2 + n) * 1024 + (sl0 ^ 32));
    }
    STAGE1(bSrc, 0, d + 16384, ts);
    STAGE1(bSrc, 1, d + 20480, ts);
    __builtin_amdgcn_s_barrier();
    asm volatile("s_waitcnt lgkmcnt(0)" ::: "memory");
    __builtin_amdgcn_sched_barrier(0);
    __builtin_amdgcn_s_setprio(1);
    #pragma unroll
    for (int m = 0; m < 4; ++m)
      #pragma unroll
      for (int n = 0; n < 2; ++n) {
        acc[m][2 + n] = __builtin_amdgcn_mfma_f32_16x16x32_bf16(aq[m][0], bq1[n][0], acc[m][2 + n], 0, 0, 0);
        acc[m][2 + n] = __builtin_amdgcn_mfma_f32_16x16x32_bf16(aq[m][1], bq1[n][1], acc[m][2 + n], 0, 0, 0);
      }
    __builtin_amdgcn_s_setprio(0);
    asm volatile("s_waitcnt vmcnt(4)" ::: "memory");
    __builtin_amdgcn_s_barrier();

    // ---- ph2 ----
    #pragma unroll
    for (int m = 0; m < 4; ++m) {
      aq[m][0] = *(const short8*)(ArHi + m * 1024 + sl0);
      aq[m][1] = *(const short8*)(ArHi + m * 1024 + (sl0 ^ 32));
    }
    STAGE1(bSrc, 2, d + 24576, ts);
    STAGE1(bSrc, 3, d + 28672, ts);
    __builtin_amdgcn_s_barrier();
    asm volatile("s_waitcnt lgkmcnt(0)" ::: "memory");
    __builtin_amdgcn_sched_barrier(0);
    __builtin_amdgcn_s_setprio(1);
    #pragma unroll
    for (int m = 0; m < 4; ++m)
      #pragma unroll
      for (int n = 0; n < 2; ++n) {
        acc[4 + m][2 + n] = __builtin_amdgcn_mfma_f32_16x16x32_bf16(aq[m][0], bq1[n][0], acc[4 + m][2 + n], 0, 0, 0);
        acc[4 + m][2 + n] = __builtin_amdgcn_mfma_f32_16x16x32_bf16(aq[m][1], bq1[n][1], acc[4 + m][2 + n], 0, 0, 0);
      }
    __builtin_amdgcn_s_setprio(0);
    __builtin_amdgcn_s_barrier();

    // ---- ph3 ----
    STAGE1(aSrc, 1, d + 4096, ts);
    STAGE1(aSrc, 3, d + 12288, ts);
    __builtin_amdgcn_s_setprio(1);
    #pragma unroll
    for (int m = 0; m < 4; ++m)
      #pragma unroll
      for (int n = 0; n < 2; ++n) {
        acc[4 + m][n] = __builtin_amdgcn_mfma_f32_16x16x32_bf16(aq[m][0], bq0[n][0], acc[4 + m][n], 0, 0, 0);
        acc[4 + m][n] = __builtin_amdgcn_mfma_f32_16x16x32_bf16(aq[m][1], bq0[n][1], acc[4 + m][n], 0, 0, 0);
      }
    __builtin_amdgcn_s_setprio(0);
    asm volatile("s_waitcnt vmcnt(2)" ::: "memory");
    __builtin_amdgcn_s_barrier();
  }
#undef STAGE1

  asm volatile("s_waitcnt vmcnt(0)" ::: "memory");

  const int crow0 = bm * 256 + wm * 128 + kq * 4;
  const int ccol0 = bn * 256 + wn * 64 + fr;
  if (EPI == 0) {
    unsigned short* C = (unsigned short*)Cout;
    #pragma unroll
    for (int m = 0; m < 8; ++m)
      #pragma unroll
      for (int n = 0; n < 4; ++n)
        #pragma unroll
        for (int r = 0; r < 4; ++r)
          C[(size_t)(crow0 + m * 16 + r) * ldc + ccol0 + n * 16] = f2bf(acc[m][n][r]);
  } else {
    float* C = (float*)Cout;
    #pragma unroll
    for (int n = 0; n < 4; ++n) {
      const float bv_ = bias[ccol0 + n * 16];
      #pragma unroll
      for (int m = 0; m < 8; ++m)
        #pragma unroll
        for (int r = 0; r < 4; ++r)
          C[(size_t)(crow0 + m * 16 + r) * ldc + ccol0 + n * 16] = acc[m][n][r] + bv_;
    }
  }
}

// ---------------- sliding-window pool (scores precomputed) ----------------
__global__ __launch_bounds__(256)
void winpool(const unsigned short* __restrict__ V,
             const float* __restrict__ S,
             unsigned short* __restrict__ P)
{
  const int lane = threadIdx.x & 63, wid = threadIdx.x >> 6;
  const int tg = (int)blockIdx.x * 4 + wid;       // 0..2047
  const int t0 = tg * 8;
  const int h = blockIdx.y;
  const float scale = 0.08838834764831845f;  // 1/sqrt(128)

  float sv[11], v0[11], v1[11];
  #pragma unroll
  for (int i = 0; i < 11; ++i) {
    const int idx = t0 - 3 + i;
    if (idx >= 0) {
      sv[i] = S[(size_t)idx * HEADS + h] * scale;
      const unsigned vv = *(const unsigned*)(V + (size_t)idx * D_IO + h * DHEAD + lane * 2);
      v0[i] = bf2f((unsigned short)(vv & 0xffffu));
      v1[i] = bf2f((unsigned short)(vv >> 16));
    } else {
      sv[i] = -3.0e38f; v0[i] = 0.f; v1[i] = 0.f;
    }
  }

  #pragma unroll
  for (int j = 0; j < 8; ++j) {
    const float mx = fmaxf(fmaxf(sv[j], sv[j + 1]), fmaxf(sv[j + 2], sv[j + 3]));
    float p0 = __expf(sv[j] - mx),     p1 = __expf(sv[j + 1] - mx);
    float p2 = __expf(sv[j + 2] - mx), p3 = __expf(sv[j + 3] - mx);
    const float inv = 1.f / (p0 + p1 + p2 + p3);
    const float o0 = (p0 * v0[j] + p1 * v0[j + 1] + p2 * v0[j + 2] + p3 * v0[j + 3]) * inv;
    const float o1 = (p0 * v1[j] + p1 * v1[j + 1] + p2 * v1[j + 2] + p3 * v1[j + 3]) * inv;
    const unsigned outw = ((unsigned)f2bf(o1) << 16) | (unsigned)f2bf(o0);
    *(unsigned*)(P + (size_t)(t0 + j) * D_IO + h * DHEAD + lane * 2) = outw;
  }
}

// ---------------- launch ----------------
extern "C" void kernel_launch(void* const* d_in, const int* in_sizes, int n_in,
                              void* d_out, int out_size, void* d_ws, size_t ws_size,
                              hipStream_t stream)
{
  const float* e_seq = (const float*)d_in[0];
  const float* q     = (const float*)d_in[1];
  const float* Wk    = (const float*)d_in[2];
  const float* Wv    = (const float*)d_in[3];
  const float* Wo    = (const float*)d_in[4];
  const float* bo    = (const float*)d_in[5];
  float* out = (float*)d_out;

  char* ws = (char*)d_ws;
  unsigned short* Ebf  = (unsigned short*)ws;                         // 64 MB (E bf16; reused as pooled)
  unsigned short* Vbf  = (unsigned short*)(ws + 67108864);            // 64 MB
  unsigned short* Wvt  = (unsigned short*)(ws + 134217728);           // 8 MB
  unsigned short* Wot  = (unsigned short*)(ws + 142606336);           // 8 MB
  unsigned short* QKbf = (unsigned short*)(ws + 150994944);           // 64 KB
  float*          Sbuf = (float*)(ws + 151060480);                    // 1 MB

  // prep: cvt E + transpose Wv,Wo + qk = per-head Wk_slice @ q
  prep<<<16512, 256, 0, stream>>>(e_seq, q, Wk, Wv, Wo, Ebf, Wvt, Wot, QKbf);

  // V = E * Wv   (M=16384, N=2048, K=2048), bf16 out
  gemm256<0><<<dim3(8, 64), 512, 0, stream>>>(Ebf, Wvt, Vbf, nullptr, 2048, 3);

  // S = E @ qk^T  ([L,16] f32)
  scores<<<L_SEQ / 64, 256, 0, stream>>>(Ebf, QKbf, Sbuf);

  // pooled (into Ebf, no longer needed)
  winpool<<<dim3(512, HEADS), 256, 0, stream>>>(Vbf, Sbuf, Ebf);

  // out = pooled * Wo + bo   (f32 out + bias)
  gemm256<1><<<dim3(8, 64), 512, 0, stream>>>(Ebf, Wot, out, bo, 2048, 3);
}